// Round 1
// baseline (265.160 us; speedup 1.0000x reference)
//
#include <hip/hip_runtime.h>
#include <math.h>

#define NUM_STEPS 128
#define N_IMP 32
#define ITERS 4
#define RPB 4   // rays per block, one 64-lane wave per ray

__device__ __forceinline__ float sigmoidf_(float x) {
    return 1.0f / (1.0f + __expf(-x));
}

__device__ __forceinline__ float sphere_sdf_at(float ox, float oy, float oz,
                                               float dx, float dy, float dz, float t) {
    float px = ox + dx * t, py = oy + dy * t, pz = oz + dz * t;
    px = fminf(fmaxf(px, -1.0f), 1.0f);
    py = fminf(fmaxf(py, -1.0f), 1.0f);
    pz = fminf(fmaxf(pz, -1.0f), 1.0f);
    return sqrtf(px * px + py * py + pz * pz) - 0.5f;
}

__global__ __launch_bounds__(RPB * 64) void neus_upsample_kernel(
    const float* __restrict__ rays_o, const float* __restrict__ rays_d,
    float* __restrict__ out, int nrays)
{
    __shared__ float zA[RPB][256], zB[RPB][256];
    __shared__ float sA[RPB][256], sB[RPB][256];
    __shared__ float alphaS[RPB][224];
    __shared__ float cdfS[RPB][226];
    __shared__ float nzS[RPB][32], nsS[RPB][32];

    const int w    = threadIdx.x >> 6;
    const int lane = threadIdx.x & 63;
    const int ray  = blockIdx.x * RPB + w;
    const bool valid = (ray < nrays);

    float ox = 0, oy = 0, oz = 0, dx = 0, dy = 0, dz = 0;
    if (valid) {
        ox = rays_o[ray * 3 + 0]; oy = rays_o[ray * 3 + 1]; oz = rays_o[ray * 3 + 2];
        float rx = rays_d[ray * 3 + 0], ry = rays_d[ray * 3 + 1], rz = rays_d[ray * 3 + 2];
        float inv = 1.0f / (sqrtf(rx * rx + ry * ry + rz * rz) + 1e-8f);
        dx = rx * inv; dy = ry * inv; dz = rz * inv;
    }

    float* zCur = zA[w]; float* zNxt = zB[w];
    float* sCur = sA[w]; float* sNxt = sB[w];

    // init: z = NEAR + (FAR-NEAR)*linspace(0,1,128), sdf of clipped pts
    if (valid) {
        for (int k = lane; k < NUM_STEPS; k += 64) {
            float zv = 0.2f + 1.8f * ((float)k * (1.0f / 127.0f));
            zCur[k] = zv;
            sCur[k] = sphere_sdf_at(ox, oy, oz, dx, dy, dz, zv);
        }
    }
    __syncthreads();

    int N = NUM_STEPS;
    for (int it = 0; it < ITERS; ++it) {
        const float inv_s = 64.0f * (float)(1 << it);
        const bool last = (it == ITERS - 1);
        const int M = N - 1;

        // ---- phase 1: per-interval alpha (embarrassingly parallel) ----
        if (valid) {
            for (int k = lane; k < M; k += 64) {
                float z0 = zCur[k], z1 = zCur[k + 1];
                float s0 = sCur[k], s1 = sCur[k + 1];
                float mid  = 0.5f * (s0 + s1);
                float cosk = (s1 - s0) / (z1 - z0 + 1e-5f);
                float cosp = 0.0f;
                if (k > 0) {
                    float zm = zCur[k - 1], sm = sCur[k - 1];
                    cosp = (s0 - sm) / (z0 - zm + 1e-5f);
                }
                float cv = fminf(cosp, cosk);
                cv = fminf(fmaxf(cv, -1000.0f), 0.0f);
                float dist = z1 - z0;
                float pe = mid - cv * dist * 0.5f;
                float ne = mid + cv * dist * 0.5f;
                float pc = sigmoidf_(pe * inv_s);
                float nc = sigmoidf_(ne * inv_s);
                alphaS[w][k] = (pc - nc + 1e-5f) / (pc + 1e-5f);
            }
        }
        __syncthreads();

        // ---- phase 2: transmittance cumprod + weight cumsum -> normalized cdf ----
        if (valid) {
            const int R  = (M + 63) >> 6;   // 2,3,3,4 over the 4 iterations
            const int k0 = lane * R;
            float a[4], q[4], wv[4];
            #pragma unroll
            for (int r = 0; r < 4; ++r) {
                int k = k0 + r;
                bool in = (r < R) && (k < M);
                a[r] = in ? alphaS[w][k] : 0.0f;
                q[r] = in ? (1.0f - a[r] + 1e-7f) : 1.0f;
            }
            float P = q[0] * q[1] * q[2] * q[3];
            // inclusive product scan across lanes
            float incP = P;
            #pragma unroll
            for (int d = 1; d < 64; d <<= 1) {
                float t = __shfl_up(incP, (unsigned)d, 64);
                if (lane >= d) incP *= t;
            }
            float T = __shfl_up(incP, 1u, 64);
            if (lane == 0) T = 1.0f;
            // per-element weights w' = alpha*T + 1e-5, local sum
            float L = 0.0f;
            #pragma unroll
            for (int r = 0; r < 4; ++r) {
                int k = k0 + r;
                bool in = (r < R) && (k < M);
                wv[r] = in ? (a[r] * T + 1e-5f) : 0.0f;
                L += wv[r];
                T *= q[r];
            }
            // inclusive sum scan across lanes
            float incL = L;
            #pragma unroll
            for (int d = 1; d < 64; d <<= 1) {
                float t = __shfl_up(incL, (unsigned)d, 64);
                if (lane >= d) incL += t;
            }
            float S    = __shfl(incL, 63, 64);
            float excL = __shfl_up(incL, 1u, 64);
            if (lane == 0) excL = 0.0f;
            float invS = 1.0f / S;
            if (lane == 0) cdfS[w][0] = 0.0f;
            float run = excL;
            #pragma unroll
            for (int r = 0; r < 4; ++r) {
                int k = k0 + r;
                if ((r < R) && (k < M)) {
                    run += wv[r];
                    cdfS[w][k + 1] = run * invS;
                }
            }
        }
        __syncthreads();

        // ---- phase 3: inverse-CDF sample 32 new z values ----
        if (valid && lane < 32) {
            float u = (float)(2 * lane + 1) * (1.0f / 64.0f);
            // searchsorted(cdf, u, side='right') over cdf[0..M]
            int lo = 0, hi = M + 1;
            while (lo < hi) {
                int mid = (lo + hi) >> 1;
                if (cdfS[w][mid] <= u) lo = mid + 1; else hi = mid;
            }
            int below = lo - 1; if (below < 0) below = 0;
            int above = (lo <= M) ? lo : M;
            float cb = cdfS[w][below], ca = cdfS[w][above];
            float denom = ca - cb;
            if (denom < 1e-5f) denom = 1.0f;
            float t  = (u - cb) / denom;
            float zb = zCur[below], za = zCur[above];
            float nz = zb + t * (za - zb);
            nzS[w][lane] = nz;
            if (!last) nsS[w][lane] = sphere_sdf_at(ox, oy, oz, dx, dy, dz, nz);
        }
        __syncthreads();

        // ---- phase 4: stable rank-merge of sorted old (N) + sorted new (32) ----
        if (valid) {
            for (int k = lane; k < N; k += 64) {
                float zv = zCur[k];
                int lo = 0, hi = 32;     // count new < zv (ties: old first)
                while (lo < hi) {
                    int mid = (lo + hi) >> 1;
                    if (nzS[w][mid] < zv) lo = mid + 1; else hi = mid;
                }
                zNxt[k + lo] = zv;
                if (!last) sNxt[k + lo] = sCur[k];
            }
            if (lane < 32) {
                float zv = nzS[w][lane];
                int lo = 0, hi = N;      // count old <= zv
                while (lo < hi) {
                    int mid = (lo + hi) >> 1;
                    if (zCur[mid] <= zv) lo = mid + 1; else hi = mid;
                }
                zNxt[lo + lane] = zv;
                if (!last) sNxt[lo + lane] = nsS[w][lane];
            }
        }
        __syncthreads();

        { float* t = zCur; zCur = zNxt; zNxt = t; }
        { float* t = sCur; sCur = sNxt; sNxt = t; }
        N += N_IMP;
    }

    // ---- write final sorted z_vals (256 per ray), coalesced ----
    if (valid) {
        size_t base = (size_t)ray * 256;
        for (int k = lane; k < 256; k += 64) {
            out[base + k] = zCur[k];
        }
    }
}

extern "C" void kernel_launch(void* const* d_in, const int* in_sizes, int n_in,
                              void* d_out, int out_size, void* d_ws, size_t ws_size,
                              hipStream_t stream) {
    const float* rays_o = (const float*)d_in[0];
    const float* rays_d = (const float*)d_in[1];
    float* out = (float*)d_out;
    const int nrays = in_sizes[0] / 3;
    const int blocks = (nrays + RPB - 1) / RPB;
    neus_upsample_kernel<<<blocks, RPB * 64, 0, stream>>>(rays_o, rays_d, out, nrays);
}

// Round 2
// 195.322 us; speedup vs baseline: 1.3576x; 1.3576x over previous
//
#include <hip/hip_runtime.h>
#include <math.h>

#define RPB 4   // rays per block, one 64-lane wave per ray; all per-ray LDS is wave-private

// Wave-local LDS ordering: all per-ray LDS is touched only by its own wave,
// so no __syncthreads needed anywhere — just drain LDS ops + pin scheduling.
__device__ __forceinline__ void wave_fence() {
    asm volatile("s_waitcnt lgkmcnt(0)" ::: "memory");
    __builtin_amdgcn_wave_barrier();
}

__device__ __forceinline__ float sigmoid_(float x) {
    return __fdividef(1.0f, 1.0f + __expf(-x));
}

__device__ __forceinline__ float sdf_at(float ox, float oy, float oz,
                                        float dx, float dy, float dz, float t) {
    float px = ox + dx * t, py = oy + dy * t, pz = oz + dz * t;
    px = fminf(fmaxf(px, -1.0f), 1.0f);
    py = fminf(fmaxf(py, -1.0f), 1.0f);
    pz = fminf(fmaxf(pz, -1.0f), 1.0f);
    return sqrtf(px * px + py * py + pz * pz) - 0.5f;
}

__global__ __launch_bounds__(RPB * 64) void neus_kernel(
    const float* __restrict__ rays_o, const float* __restrict__ rays_d,
    float* __restrict__ out, int nrays)
{
    __shared__ __align__(16) float zS[RPB][260];
    __shared__ __align__(16) float sS[RPB][260];
    __shared__ __align__(16) float cdfS[RPB][228];
    __shared__ __align__(16) int   cntS[RPB][228];

    const int w    = threadIdx.x >> 6;
    const int lane = threadIdx.x & 63;
    const int ray  = blockIdx.x * RPB + w;
    if (ray >= nrays) return;   // safe: no block-wide barriers anywhere

    float* z   = zS[w];
    float* s   = sS[w];
    float* cdf = cdfS[w];
    int*   cnt = cntS[w];

    const float ox = rays_o[ray * 3 + 0], oy = rays_o[ray * 3 + 1], ozr = rays_o[ray * 3 + 2];
    float rx = rays_d[ray * 3 + 0], ry = rays_d[ray * 3 + 1], rz = rays_d[ray * 3 + 2];
    float inv = __fdividef(1.0f, sqrtf(rx * rx + ry * ry + rz * rz) + 1e-8f);
    const float dx = rx * inv, dy = ry * inv, dz = rz * inv;

    // init: z = 0.2 + 1.8*linspace(0,1,128), sdf at clipped points
    for (int k = lane; k < 128; k += 64) {
        float zv = 0.2f + 1.8f * ((float)k * (1.0f / 127.0f));
        z[k] = zv;
        s[k] = sdf_at(ox, oy, ozr, dx, dy, dz, zv);
    }
    wave_fence();

    int N = 128;
    for (int it = 0; it < 4; ++it) {
        const float inv_s = 64.0f * (float)(1 << it);
        const bool  last  = (it == 3);
        const int   M  = N - 1;
        const int   R  = (M + 63) >> 6;   // intervals per lane: 2,3,3,4
        const int   k0 = lane * R;

        // ---- fused alpha + transmittance/weight scans -> normalized cdf ----
        float a[4], q[4];
        {
            float zm = 0.f, sm = 0.f, z0 = 0.f, s0 = 0.f;
            if (k0 > 0 && k0 - 1 < N) { zm = z[k0 - 1]; sm = s[k0 - 1]; }
            if (k0 < N) { z0 = z[k0]; s0 = s[k0]; }
            #pragma unroll
            for (int r = 0; r < 4; ++r) {
                int k = k0 + r;
                bool in = (r < R) && (k < M);
                float z1 = 0.f, s1 = 0.f;
                if (in) { z1 = z[k + 1]; s1 = s[k + 1]; }
                float al = 0.f;
                if (in) {
                    float mid  = 0.5f * (s0 + s1);
                    float cosk = __fdividef(s1 - s0, z1 - z0 + 1e-5f);
                    float cosp = (k > 0) ? __fdividef(s0 - sm, z0 - zm + 1e-5f) : 0.0f;
                    float cv = fminf(cosp, cosk);
                    cv = fminf(fmaxf(cv, -1000.0f), 0.0f);
                    float hd = 0.5f * (z1 - z0);
                    float pc = sigmoid_((mid - cv * hd) * inv_s);
                    float nc = sigmoid_((mid + cv * hd) * inv_s);
                    al = __fdividef(pc - nc + 1e-5f, pc + 1e-5f);
                }
                a[r] = al;
                q[r] = in ? (1.0f - al + 1e-7f) : 1.0f;
                zm = z0; sm = s0; z0 = z1; s0 = s1;  // roll (idle lanes roll junk, unused)
            }
        }
        // exclusive cumprod of q across the wave (blocked)
        float P = q[0] * q[1] * q[2] * q[3];
        float incP = P;
        #pragma unroll
        for (int d = 1; d < 64; d <<= 1) {
            float t = __shfl_up(incP, (unsigned)d, 64);
            if (lane >= d) incP *= t;
        }
        float T = __shfl_up(incP, 1u, 64);
        if (lane == 0) T = 1.0f;
        float wv[4], L = 0.f;
        #pragma unroll
        for (int r = 0; r < 4; ++r) {
            int k = k0 + r;
            bool in = (r < R) && (k < M);
            wv[r] = in ? (a[r] * T + 1e-5f) : 0.0f;
            L += wv[r];
            T *= q[r];
        }
        float incL = L;
        #pragma unroll
        for (int d = 1; d < 64; d <<= 1) {
            float t = __shfl_up(incL, (unsigned)d, 64);
            if (lane >= d) incL += t;
        }
        float S    = __shfl(incL, 63, 64);
        float excL = __shfl_up(incL, 1u, 64);
        if (lane == 0) excL = 0.0f;
        float invS = __fdividef(1.0f, S);
        if (lane == 0) cdf[0] = 0.0f;
        {
            float run = excL;
            #pragma unroll
            for (int r = 0; r < 4; ++r) {
                int k = k0 + r;
                if ((r < R) && (k < M)) {
                    run += wv[r];
                    cdf[k + 1] = run * invS;
                }
            }
        }
        wave_fence();

        // ---- read my old elems into regs (blocked), zero histogram ----
        const int R2 = (N + 63) >> 6;
        const int b0 = lane * R2;
        float oz[4], os[4];
        #pragma unroll
        for (int r = 0; r < 4; ++r) {
            int k = b0 + r;
            bool in = (r < R2) && (k < N);
            oz[r] = in ? z[k] : 0.f;
            os[r] = (!last && in) ? s[k] : 0.f;
        }
        for (int k = lane; k < N; k += 64) cnt[k] = 0;  // cnt[N] never read -> no need to zero

        // ---- inverse-CDF sample 32 new z; rank among old comes free ----
        float nz = 0.f, ns = 0.f;
        int rr = 0;
        if (lane < 32) {
            float u = (float)(2 * lane + 1) * 0.015625f;
            int lo = 0, hi = M + 1;          // searchsorted(cdf[0..M], u, right)
            while (lo < hi) {
                int mid = (lo + hi) >> 1;
                if (cdf[mid] <= u) lo = mid + 1; else hi = mid;
            }
            int below = lo - 1;              // lo >= 1 since cdf[0]=0 <= u
            float cb = cdf[below], ca = cdf[lo];
            float denom = ca - cb;
            denom = (denom < 1e-5f) ? 1.0f : denom;
            float t = __fdividef(u - cb, denom);
            float zb = z[below], za = z[lo];
            nz = zb + t * (za - zb);
            rr = below + 1 + ((nz >= za) ? 1 : 0);   // count(old <= nz)
            if (!last) ns = sdf_at(ox, oy, ozr, dx, dy, dz, nz);
        }
        wave_fence();

        if (lane < 32) atomicAdd(&cnt[rr], 1);
        wave_fence();

        // ---- scan histogram: c_k = #{new i : rank_i <= k} ----
        int cl[4], lsum = 0;
        #pragma unroll
        for (int r = 0; r < 4; ++r) {
            int k = b0 + r;
            bool in = (r < R2) && (k < N);
            cl[r] = in ? cnt[k] : 0;
            lsum += cl[r];
        }
        int incC = lsum;
        #pragma unroll
        for (int d = 1; d < 64; d <<= 1) {
            int t = __shfl_up(incC, (unsigned)d, 64);
            if (lane >= d) incC += t;
        }
        int base = incC - lsum;   // exclusive prefix across lanes
        wave_fence();

        // ---- in-place scatter (bijection; every source value lives in regs) ----
        {
            int c = base;
            #pragma unroll
            for (int r = 0; r < 4; ++r) {
                int k = b0 + r;
                if ((r < R2) && (k < N)) {
                    c += cl[r];                  // inclusive prefix up to k
                    z[k + c] = oz[r];
                    if (!last) s[k + c] = os[r];
                }
            }
        }
        if (lane < 32) {
            z[rr + lane] = nz;                   // stable: equal news keep index order
            if (!last) s[rr + lane] = ns;
        }
        wave_fence();

        N += 32;
    }

    // ---- coalesced vectorized output: 256 floats per ray ----
    float4 zv4 = *reinterpret_cast<const float4*>(&z[lane * 4]);
    *reinterpret_cast<float4*>(&out[(size_t)ray * 256 + (size_t)lane * 4]) = zv4;
}

extern "C" void kernel_launch(void* const* d_in, const int* in_sizes, int n_in,
                              void* d_out, int out_size, void* d_ws, size_t ws_size,
                              hipStream_t stream) {
    const float* rays_o = (const float*)d_in[0];
    const float* rays_d = (const float*)d_in[1];
    float* out = (float*)d_out;
    const int nrays = in_sizes[0] / 3;
    const int blocks = (nrays + RPB - 1) / RPB;
    neus_kernel<<<blocks, RPB * 64, 0, stream>>>(rays_o, rays_d, out, nrays);
}